// Round 6
// baseline (424.042 us; speedup 1.0000x reference)
//
#include <hip/hip_runtime.h>
#include <hip/hip_bf16.h>
#include <math.h>

#define NNODES 50000
#define NEDGES 640000
#define DIM    128
#define PEDIM  37
#define KTOT   165   // DIM + PEDIM
#define KPAD   200   // bf16 row stride for A and B (400 B = 25 int4, 16B-aligned)
#define HSTR   136   // LDS repack stride (272 B, 16B-aligned, conflict-benign)
#define NLAYERS 3
#define NSB    ((NNODES + 255) / 256)     // 196 scan blocks
#define NPACKB ((NNODES * 25 + 255) / 256) // 4883 pack blocks
#define NBN    (NNODES * DIM / 256)        // 25000 BN-apply blocks

using bf16x8 = __attribute__((ext_vector_type(8))) short;
using f32x4  = __attribute__((ext_vector_type(4))) float;

static constexpr size_t alignup(size_t x) { return (x + 255) & ~size_t(255); }
static constexpr size_t OFF_X    = 0;                                              // fp32 x (residual)
static constexpr size_t OFF_H    = alignup(OFF_X   + (size_t)NNODES * DIM * 4);    // bf16 H
static constexpr size_t OFF_O    = alignup(OFF_H   + (size_t)NNODES * DIM * 2);    // fp32 out
static constexpr size_t OFF_AB   = alignup(OFF_O   + (size_t)NNODES * DIM * 4);    // bf16 A=[x|PE|0]
static constexpr size_t OFF_HL   = alignup(OFF_AB  + (size_t)NNODES * KPAD * 2);
static constexpr size_t OFF_HR   = alignup(OFF_HL  + (size_t)NNODES * 4);
static constexpr size_t OFF_OFFS = alignup(OFF_HR  + (size_t)NNODES * 4);
static constexpr size_t OFF_CUR  = alignup(OFF_OFFS + (size_t)(NNODES + 1) * 4);
static constexpr size_t OFF_CSR  = alignup(OFF_CUR + (size_t)NNODES * 4);
static constexpr size_t OFF_BTG  = alignup(OFF_CSR + (size_t)NEDGES * 4);
static constexpr size_t OFF_B2   = alignup(OFF_BTG + (size_t)DIM * KPAD * 2);
static constexpr size_t OFF_ET   = alignup(OFF_B2  + (size_t)DIM * 4);
static constexpr size_t OFF_GS   = alignup(OFF_ET  + 16 * 4);                      // 4*128 floats: gs0,gsq0,gs1,gsq1
static constexpr size_t OFF_BS   = alignup(OFF_GS  + 512 * 4);
static constexpr size_t OFF_BP   = alignup(OFF_BS  + 256 * 4);
static constexpr size_t WS_NEED  = alignup(OFF_BP  + 256 * 4);

__device__ inline unsigned short f2b(float f) {
    union { float f; unsigned int u; } x; x.f = f;
    unsigned int r = x.u + 0x7FFFu + ((x.u >> 16) & 1u);
    return (unsigned short)(r >> 16);
}
__device__ inline unsigned int pack2(float a, float b) {
    return (unsigned int)f2b(a) | ((unsigned int)f2b(b) << 16);
}

__device__ inline void gload_lds16(const void* g, void* l) {
    __builtin_amdgcn_global_load_lds((const __attribute__((address_space(1))) void*)g,
                                     (__attribute__((address_space(3))) void*)l, 16, 0, 0);
}

// ---------------- CSR build ----------------

__global__ void k_zero_int(int* __restrict__ p, int n) {
    for (int i = blockIdx.x * blockDim.x + threadIdx.x; i < n; i += gridDim.x * blockDim.x)
        p[i] = 0;
}

__global__ void k_count(const int* __restrict__ dstv, int* __restrict__ cnt) {
    for (int e = blockIdx.x * blockDim.x + threadIdx.x; e < NEDGES; e += gridDim.x * blockDim.x)
        atomicAdd(&cnt[dstv[e]], 1);
}

__global__ __launch_bounds__(256) void k_scan1(const int* __restrict__ cnt, int* __restrict__ bsum) {
    __shared__ int ls[256];
    const int i = blockIdx.x * 256 + threadIdx.x;
    ls[threadIdx.x] = (i < NNODES) ? cnt[i] : 0;
    __syncthreads();
    for (int d = 128; d > 0; d >>= 1) {
        if (threadIdx.x < d) ls[threadIdx.x] += ls[threadIdx.x + d];
        __syncthreads();
    }
    if (threadIdx.x == 0) bsum[blockIdx.x] = ls[0];
}

__global__ __launch_bounds__(256) void k_scan2(const int* __restrict__ bsum,
                                               int* __restrict__ bpre, int* __restrict__ offs) {
    __shared__ int ls[256];
    const int t = threadIdx.x;
    ls[t] = (t < NSB) ? bsum[t] : 0;
    __syncthreads();
    for (int d = 1; d < 256; d <<= 1) {
        int v = (t >= d) ? ls[t - d] : 0;
        __syncthreads();
        ls[t] += v;
        __syncthreads();
    }
    bpre[t] = (t == 0) ? 0 : ls[t - 1];
    if (t == 255) offs[NNODES] = ls[255];
}

__global__ __launch_bounds__(256) void k_scan3(const int* __restrict__ cnt,
                                               const int* __restrict__ bpre,
                                               int* __restrict__ offs, int* __restrict__ cur) {
    __shared__ int ls[256];
    const int i = blockIdx.x * 256 + threadIdx.x;
    const int v = (i < NNODES) ? cnt[i] : 0;
    ls[threadIdx.x] = v;
    __syncthreads();
    for (int d = 1; d < 256; d <<= 1) {
        int x = (threadIdx.x >= d) ? ls[threadIdx.x - d] : 0;
        __syncthreads();
        ls[threadIdx.x] += x;
        __syncthreads();
    }
    if (i < NNODES) {
        const int excl = ls[threadIdx.x] - v + bpre[blockIdx.x];
        offs[i] = excl;
        cur[i] = excl;
    }
}

__global__ void k_fill(const int* __restrict__ srcv, const int* __restrict__ dstv,
                       const int* __restrict__ attr, int* __restrict__ cur,
                       int* __restrict__ csr) {
    for (int e = blockIdx.x * blockDim.x + threadIdx.x; e < NEDGES; e += gridDim.x * blockDim.x) {
        int d = dstv[e];
        int pos = atomicAdd(&cur[d], 1);
        csr[pos] = (srcv[e] & 0xFFFF) | (attr[e] << 16);
    }
}

// ---------------- shared params body ----------------
__device__ inline void params_body(int pb, int tid,
    const float* __restrict__ linW, const float* __restrict__ peW,
    const float* __restrict__ peb, const float* __restrict__ attn_e,
    const float* __restrict__ edge_emb,
    unsigned short* __restrict__ Btg, float* __restrict__ b2, float* __restrict__ et) {
    if (pb < 100) {
        const int idx = pb * 256 + tid;   // 0..25599
        const int j = idx & 127;
        const int k = idx >> 7;           // 0..199
        float v = 0.f;
        if (k < DIM) {
            v = linW[k * DIM + j];
        } else if (k < KTOT) {
            const int p = k - DIM;
            float s = 0.f;
            #pragma unroll 8
            for (int d = 0; d < DIM; ++d) s = fmaf(peW[p * DIM + d], linW[d * DIM + j], s);
            v = s;
        }
        Btg[(size_t)j * KPAD + k] = f2b(v);
    } else {
        if (tid < DIM) {
            float s = 0.f;
            #pragma unroll 8
            for (int d = 0; d < DIM; ++d) s = fmaf(peb[d], linW[d * DIM + tid], s);
            b2[tid] = s;
        } else if (tid < DIM + 9) {
            const int e = tid - DIM;
            float s = 0.f;
            #pragma unroll 8
            for (int d = 0; d < DIM; ++d) s = fmaf(edge_emb[e * DIM + d], attn_e[d], s);
            et[e] = s;
        }
    }
}

// ---------------- pack A + layer-0 params + zero BN accumulators ----------------
__global__ __launch_bounds__(256) void k_pack(
    const float* __restrict__ X, const float* __restrict__ PE,
    const float* __restrict__ linW, const float* __restrict__ peW,
    const float* __restrict__ peb, const float* __restrict__ attn_e,
    const float* __restrict__ edge_emb,
    unsigned short* __restrict__ Ab, unsigned short* __restrict__ Btg,
    float* __restrict__ b2, float* __restrict__ et, float* __restrict__ gs) {
    if ((int)blockIdx.x < NPACKB) {
        const int idx = blockIdx.x * 256 + threadIdx.x;
        if (idx >= NNODES * 25) return;
        const int r = idx / 25, kc = idx % 25;
        int4 pk;
        if (kc < 16) {
            const float4* xp = (const float4*)&X[(size_t)r * DIM + kc * 8];
            const float4 v0 = xp[0], v1 = xp[1];
            pk.x = pack2(v0.x, v0.y); pk.y = pack2(v0.z, v0.w);
            pk.z = pack2(v1.x, v1.y); pk.w = pack2(v1.z, v1.w);
        } else {
            float f[8];
            #pragma unroll
            for (int i = 0; i < 8; ++i) {
                const int k = kc * 8 + i;
                f[i] = (k < KTOT) ? PE[(size_t)r * PEDIM + (k - DIM)] : 0.f;
            }
            pk.x = pack2(f[0], f[1]); pk.y = pack2(f[2], f[3]);
            pk.z = pack2(f[4], f[5]); pk.w = pack2(f[6], f[7]);
        }
        ((int4*)(Ab + (size_t)r * KPAD))[kc] = pk;
    } else {
        const int pb = blockIdx.x - NPACKB;
        if (pb == 100) {
            gs[threadIdx.x] = 0.f;
            gs[threadIdx.x + 256] = 0.f;
        }
        params_body(pb, threadIdx.x, linW, peW, peb, attn_e, edge_emb, Btg, b2, et);
    }
}

// ---------------- MFMA GEMM: H(bf16) = A @ B + b2, plus hl/hr ----------------
// BM=64, N=128, K=192. Only B in LDS (51.2 KB -> 3 blocks/CU); A frags global->VGPR.
__global__ __launch_bounds__(256) void k_gemm(
    const unsigned short* __restrict__ Ab16, const unsigned short* __restrict__ Btg,
    const float* __restrict__ b2, const float* __restrict__ attn_l,
    const float* __restrict__ attn_r,
    unsigned short* __restrict__ H, float* __restrict__ HL, float* __restrict__ HR) {
    __shared__ unsigned short Bls[DIM * KPAD];   // 51.2 KB
    const int tid = threadIdx.x;
    const int row0 = blockIdx.x * 64;
    const int w = tid >> 6, l = tid & 63;
    const int c = l & 15;     // A-row-in-tile / B-col / D-col
    const int g = l >> 4;     // k-subgroup / D-row-group

    // issue A fragment loads first (overlap with B staging). OOB rows read
    // garbage inside ws (harmless; outputs guarded), last block only.
    const unsigned short* aBase = Ab16 + (size_t)(row0 + w * 16 + c) * KPAD + g * 8;
    bf16x8 a0 = *(const bf16x8*)(aBase + 0 * 32);
    bf16x8 a1 = *(const bf16x8*)(aBase + 1 * 32);
    bf16x8 a2 = *(const bf16x8*)(aBase + 2 * 32);
    bf16x8 a3 = *(const bf16x8*)(aBase + 3 * 32);
    bf16x8 a4 = *(const bf16x8*)(aBase + 4 * 32);
    bf16x8 a5 = *(const bf16x8*)(aBase + 5 * 32);

    {   // stage B: 3200 int4, linear
        const int4* gb = (const int4*)Btg;
        int4* lb = (int4*)Bls;
        for (int i = tid; i < 3200; i += 256) gload_lds16(gb + i, lb + i);
    }
    __syncthreads();

    f32x4 zero4 = {0.f, 0.f, 0.f, 0.f};
    f32x4 acc[8];
    #pragma unroll
    for (int t = 0; t < 8; ++t) acc[t] = zero4;

    #pragma unroll
    for (int t = 0; t < 8; ++t) {
        const unsigned short* bRow = Bls + (size_t)(t * 16 + c) * KPAD + g * 8;
        acc[t] = __builtin_amdgcn_mfma_f32_16x16x32_bf16(a0, *(const bf16x8*)(bRow + 0 * 32), acc[t], 0, 0, 0);
        acc[t] = __builtin_amdgcn_mfma_f32_16x16x32_bf16(a1, *(const bf16x8*)(bRow + 1 * 32), acc[t], 0, 0, 0);
        acc[t] = __builtin_amdgcn_mfma_f32_16x16x32_bf16(a2, *(const bf16x8*)(bRow + 2 * 32), acc[t], 0, 0, 0);
        acc[t] = __builtin_amdgcn_mfma_f32_16x16x32_bf16(a3, *(const bf16x8*)(bRow + 3 * 32), acc[t], 0, 0, 0);
        acc[t] = __builtin_amdgcn_mfma_f32_16x16x32_bf16(a4, *(const bf16x8*)(bRow + 4 * 32), acc[t], 0, 0, 0);
        acc[t] = __builtin_amdgcn_mfma_f32_16x16x32_bf16(a5, *(const bf16x8*)(bRow + 5 * 32), acc[t], 0, 0, 0);
    }

    float b2v[8], alv[8], arv[8];
    #pragma unroll
    for (int t = 0; t < 8; ++t) {
        b2v[t] = b2[t * 16 + c];
        alv[t] = attn_l[t * 16 + c];
        arv[t] = attn_r[t * 16 + c];
    }
    #pragma unroll
    for (int t = 0; t < 8; ++t)
        #pragma unroll
        for (int j = 0; j < 4; ++j) acc[t][j] += b2v[t];

    #pragma unroll
    for (int j = 0; j < 4; ++j) {
        float sl = 0.f, sr = 0.f;
        #pragma unroll
        for (int t = 0; t < 8; ++t) { sl = fmaf(acc[t][j], alv[t], sl); sr = fmaf(acc[t][j], arv[t], sr); }
        #pragma unroll
        for (int m = 1; m < 16; m <<= 1) {
            sl += __shfl_xor(sl, m, 64);
            sr += __shfl_xor(sr, m, 64);
        }
        const int grow = row0 + w * 16 + g * 4 + j;
        if (grow < NNODES && c == 0) { HL[grow] = sl; HR[grow] = sr; }
    }

    // repack D tile -> bf16 via LDS (reuse Bls), then coalesced store
    __syncthreads();
    unsigned short* Hls = Bls;
    #pragma unroll
    for (int t = 0; t < 8; ++t)
        #pragma unroll
        for (int j = 0; j < 4; ++j)
            Hls[(w * 16 + g * 4 + j) * HSTR + t * 16 + c] = f2b(acc[t][j]);
    __syncthreads();
    #pragma unroll
    for (int kb = 0; kb < 4; ++kb) {
        const int idx = tid + kb * 256;         // 0..1023
        const int r = idx >> 4, kc = idx & 15;
        const int grow = row0 + r;
        if (grow < NNODES) {
            const int4 v = *(const int4*)(Hls + r * HSTR + kc * 8);
            ((int4*)(H + ((size_t)grow << 7)))[kc] = v;
        }
    }
}

// ---------------- per-node softmax + aggregation: 16 lanes per node ----------------
// FINAL=0: OUT = agg + bias (fp32 obuf) + BN-stat accumulation into gs.
// FINAL=1: OUT = agg + bias + xprev -> d_out.
template<int FINAL>
__global__ __launch_bounds__(256) void k_agg(
    const int* __restrict__ offs, const int* __restrict__ csr,
    const float* __restrict__ HL, const float* __restrict__ HR,
    const float* __restrict__ et, const unsigned short* __restrict__ H,
    const float* __restrict__ bias, const float* __restrict__ xprev,
    float* __restrict__ OUT, float* __restrict__ gs) {
    __shared__ float sgs[256];
    const int tid = threadIdx.x;
    if (FINAL == 0) {
        sgs[tid] = 0.f;
        __syncthreads();
    }
    const int g = tid & 15;
    const int node = blockIdx.x * 16 + (tid >> 4);   // grid exact: always < NNODES
    const int off0 = offs[node];
    const int deg = offs[node + 1] - off0;
    const float hri = HR[node];

    float f[8];
    #pragma unroll
    for (int i = 0; i < 8; ++i) f[i] = 0.f;

    if (deg <= 64) {
        float al[4];
        int sr[4];
        float mx = -1e30f;
        #pragma unroll
        for (int ch = 0; ch < 4; ++ch) {
            const int j = ch * 16 + g;
            if (j < deg) {
                const int en = csr[off0 + j];
                float a = HL[en & 0xFFFF] + hri + et[en >> 16];
                a = a > 0.f ? a : 0.2f * a;
                al[ch] = a; sr[ch] = en & 0xFFFF;
                mx = fmaxf(mx, a);
            } else { al[ch] = -1e30f; sr[ch] = 0; }
        }
        #pragma unroll
        for (int m = 1; m < 16; m <<= 1) mx = fmaxf(mx, __shfl_xor(mx, m, 16));
        float s = 0.f;
        #pragma unroll
        for (int ch = 0; ch < 4; ++ch) {
            const float e = (ch * 16 + g < deg) ? __expf(al[ch] - mx) : 0.f;
            al[ch] = e;
            s += e;
        }
        #pragma unroll
        for (int m = 1; m < 16; m <<= 1) s += __shfl_xor(s, m, 16);
        const float invd = (deg > 0) ? 1.f / s : 0.f;
        #pragma unroll
        for (int ch = 0; ch < 4; ++ch) al[ch] *= invd;

        // accumulate: broadcast weight+src within the 16-lane group
        #pragma unroll
        for (int ch = 0; ch < 4; ++ch) {
            const int base = ch * 16;
            if (base < deg) {
                const float wch = al[ch];
                const int sch = sr[ch];
                const int cnt = (deg - base < 16) ? deg - base : 16;
                for (int ln = 0; ln < cnt; ++ln) {
                    const float wgt = __shfl(wch, ln, 16);
                    const int ss = __shfl(sch, ln, 16);
                    const int4 hv = *(const int4*)(H + ((size_t)ss << 7) + (g << 3));
                    const unsigned int ux = hv.x, uy = hv.y, uz = hv.z, uw = hv.w;
                    f[0] = fmaf(wgt, __uint_as_float(ux << 16), f[0]);
                    f[1] = fmaf(wgt, __uint_as_float(ux & 0xFFFF0000u), f[1]);
                    f[2] = fmaf(wgt, __uint_as_float(uy << 16), f[2]);
                    f[3] = fmaf(wgt, __uint_as_float(uy & 0xFFFF0000u), f[3]);
                    f[4] = fmaf(wgt, __uint_as_float(uz << 16), f[4]);
                    f[5] = fmaf(wgt, __uint_as_float(uz & 0xFFFF0000u), f[5]);
                    f[6] = fmaf(wgt, __uint_as_float(uw << 16), f[6]);
                    f[7] = fmaf(wgt, __uint_as_float(uw & 0xFFFF0000u), f[7]);
                }
            }
        }
    } else {
        // rare fallback: strided recompute
        float mx = -1e30f;
        for (int j = g; j < deg; j += 16) {
            const int en = csr[off0 + j];
            float a = HL[en & 0xFFFF] + hri + et[en >> 16];
            a = a > 0.f ? a : 0.2f * a;
            mx = fmaxf(mx, a);
        }
        #pragma unroll
        for (int m = 1; m < 16; m <<= 1) mx = fmaxf(mx, __shfl_xor(mx, m, 16));
        float s = 0.f;
        for (int j = g; j < deg; j += 16) {
            const int en = csr[off0 + j];
            float a = HL[en & 0xFFFF] + hri + et[en >> 16];
            a = a > 0.f ? a : 0.2f * a;
            s += __expf(a - mx);
        }
        #pragma unroll
        for (int m = 1; m < 16; m <<= 1) s += __shfl_xor(s, m, 16);
        const float invd = 1.f / s;
        for (int j = 0; j < deg; ++j) {
            const int en = csr[off0 + j];
            const int ss = en & 0xFFFF;
            float a = HL[ss] + hri + et[en >> 16];
            a = a > 0.f ? a : 0.2f * a;
            const float wgt = __expf(a - mx) * invd;
            const int4 hv = *(const int4*)(H + ((size_t)ss << 7) + (g << 3));
            const unsigned int ux = hv.x, uy = hv.y, uz = hv.z, uw = hv.w;
            f[0] = fmaf(wgt, __uint_as_float(ux << 16), f[0]);
            f[1] = fmaf(wgt, __uint_as_float(ux & 0xFFFF0000u), f[1]);
            f[2] = fmaf(wgt, __uint_as_float(uy << 16), f[2]);
            f[3] = fmaf(wgt, __uint_as_float(uy & 0xFFFF0000u), f[3]);
            f[4] = fmaf(wgt, __uint_as_float(uz << 16), f[4]);
            f[5] = fmaf(wgt, __uint_as_float(uz & 0xFFFF0000u), f[5]);
            f[6] = fmaf(wgt, __uint_as_float(uw << 16), f[6]);
            f[7] = fmaf(wgt, __uint_as_float(uw & 0xFFFF0000u), f[7]);
        }
    }

    // epilogue: bias (+residual), write, (stats)
    const float* bp = bias + (g << 3);
    float* op = OUT + ((size_t)node << 7) + (g << 3);
    float o[8];
    #pragma unroll
    for (int i = 0; i < 8; ++i) o[i] = f[i] + bp[i];
    if (FINAL) {
        const float* xp = xprev + ((size_t)node << 7) + (g << 3);
        #pragma unroll
        for (int i = 0; i < 8; ++i) o[i] += xp[i];
    }
    *(float4*)(op)     = make_float4(o[0], o[1], o[2], o[3]);
    *(float4*)(op + 4) = make_float4(o[4], o[5], o[6], o[7]);

    if (FINAL == 0) {
        #pragma unroll
        for (int i = 0; i < 8; ++i) {
            atomicAdd(&sgs[(g << 3) + i], o[i]);
            atomicAdd(&sgs[128 + (g << 3) + i], o[i] * o[i]);
        }
        __syncthreads();
        atomicAdd(&gs[tid], sgs[tid]);
    }
}

// ---------------- BN apply + residual + A-repack, fused with NEXT layer's params ----------------
__global__ __launch_bounds__(256) void k_apply_bn_params(
    const float* __restrict__ OUT, const float* __restrict__ XPREV,
    const float* __restrict__ gs, const float* __restrict__ gamma,
    const float* __restrict__ beta,
    float* __restrict__ XNEXT, unsigned short* __restrict__ Ab,
    const float* __restrict__ linW, const float* __restrict__ peW,
    const float* __restrict__ peb, const float* __restrict__ attn_e,
    const float* __restrict__ edge_emb,
    unsigned short* __restrict__ Btg, float* __restrict__ b2, float* __restrict__ et) {
    if ((int)blockIdx.x < NBN) {
        const int idx = blockIdx.x * 256 + threadIdx.x;
        const int r = idx >> 7, c = idx & 127;
        const float mu = gs[c] * (1.f / NNODES);
        const float var = gs[128 + c] * (1.f / NNODES) - mu * mu;
        const float sc = gamma[c] * rsqrtf(var + 1e-5f);
        const float xn = (OUT[idx] - mu) * sc + beta[c] + XPREV[idx];
        XNEXT[idx] = xn;
        Ab[(size_t)r * KPAD + c] = f2b(xn);
    } else {
        params_body(blockIdx.x - NBN, threadIdx.x, linW, peW, peb, attn_e, edge_emb, Btg, b2, et);
    }
}

// ---------------- host ----------------
extern "C" void kernel_launch(void* const* d_in, const int* in_sizes, int n_in,
                              void* d_out, int out_size, void* d_ws, size_t ws_size,
                              hipStream_t stream) {
    const float* X_n      = (const float*)d_in[0];
    const float* PE       = (const float*)d_in[1];
    const int*   eidx     = (const int*)d_in[2];
    const int*   eattr    = (const int*)d_in[3];
    const float* edge_emb = (const float*)d_in[4];
    const float* pe_W     = (const float*)d_in[5];
    const float* pe_b     = (const float*)d_in[6];
    const float* lin_W    = (const float*)d_in[7];
    const float* attn_l   = (const float*)d_in[8];
    const float* attn_r   = (const float*)d_in[9];
    const float* attn_e   = (const float*)d_in[10];
    const float* bias     = (const float*)d_in[11];
    const float* bng      = (const float*)d_in[12];
    const float* bnb      = (const float*)d_in[13];

    if (ws_size < WS_NEED) return;

    char* ws = (char*)d_ws;
    float* xbuf   = (float*)(ws + OFF_X);
    unsigned short* hbuf = (unsigned short*)(ws + OFF_H);
    float* obuf   = (float*)(ws + OFF_O);
    unsigned short* Ab16 = (unsigned short*)(ws + OFF_AB);
    float* hl     = (float*)(ws + OFF_HL);
    float* hr     = (float*)(ws + OFF_HR);
    int*   offs   = (int*)(ws + OFF_OFFS);
    int*   cur    = (int*)(ws + OFF_CUR);
    int*   csr    = (int*)(ws + OFF_CSR);
    unsigned short* Btg = (unsigned short*)(ws + OFF_BTG);
    float* b2     = (float*)(ws + OFF_B2);
    float* et     = (float*)(ws + OFF_ET);
    float* gs     = (float*)(ws + OFF_GS);   // gs + 256*l for layer l
    int*   bsum   = (int*)(ws + OFF_BS);
    int*   bpre   = (int*)(ws + OFF_BP);

    const int* srcv = eidx;
    const int* dstv = eidx + NEDGES;

    hipLaunchKernelGGL(k_zero_int, dim3(256), dim3(256), 0, stream, cur, NNODES);
    hipLaunchKernelGGL(k_count, dim3(1024), dim3(256), 0, stream, dstv, cur);
    hipLaunchKernelGGL(k_scan1, dim3(NSB), dim3(256), 0, stream, cur, bsum);
    hipLaunchKernelGGL(k_scan2, dim3(1), dim3(256), 0, stream, bsum, bpre, offs);
    hipLaunchKernelGGL(k_scan3, dim3(NSB), dim3(256), 0, stream, cur, bpre, offs, cur);
    hipLaunchKernelGGL(k_fill, dim3(1024), dim3(256), 0, stream, srcv, dstv, eattr, cur, csr);
    hipLaunchKernelGGL(k_pack, dim3(NPACKB + 101), dim3(256), 0, stream,
                       X_n, PE, lin_W, pe_W, pe_b, attn_e, edge_emb,
                       Ab16, Btg, b2, et, gs);

    const float* xin = X_n;
    for (int l = 0; l < NLAYERS; ++l) {
        hipLaunchKernelGGL(k_gemm, dim3((NNODES + 63) / 64), dim3(256), 0, stream,
                           Ab16, Btg, b2, attn_l + (size_t)l * DIM, attn_r + (size_t)l * DIM,
                           hbuf, hl, hr);
        if (l < NLAYERS - 1) {
            hipLaunchKernelGGL((k_agg<0>), dim3(NNODES / 16), dim3(256), 0, stream,
                               offs, csr, hl, hr, et, hbuf, bias + (size_t)l * DIM,
                               (const float*)nullptr, obuf, gs + 256 * l);
            const int ln = l + 1;
            hipLaunchKernelGGL(k_apply_bn_params, dim3(NBN + 101), dim3(256), 0, stream,
                               obuf, xin, gs + 256 * l, bng + (size_t)l * DIM, bnb + (size_t)l * DIM,
                               xbuf, Ab16,
                               lin_W + (size_t)ln * DIM * DIM, pe_W + (size_t)ln * PEDIM * DIM,
                               pe_b + (size_t)ln * DIM, attn_e + (size_t)ln * DIM,
                               edge_emb + (size_t)ln * 9 * DIM,
                               Btg, b2, et);
            xin = xbuf;
        } else {
            hipLaunchKernelGGL((k_agg<1>), dim3(NNODES / 16), dim3(256), 0, stream,
                               offs, csr, hl, hr, et, hbuf, bias + (size_t)l * DIM,
                               xin, (float*)d_out, (float*)nullptr);
        }
    }
}

// Round 7
// 358.796 us; speedup vs baseline: 1.1818x; 1.1818x over previous
//
#include <hip/hip_runtime.h>
#include <hip/hip_bf16.h>
#include <math.h>

#define NNODES 50000
#define NEDGES 640000
#define DIM    128
#define PEDIM  37
#define KTOT   165   // DIM + PEDIM
#define KPAD   200   // bf16 row stride for A and B (400 B = 25 int4, 16B-aligned)
#define HSTR   136   // LDS repack stride (272 B, 16B-aligned, conflict-benign)
#define NLAYERS 3
#define NSB    ((NNODES + 255) / 256)     // 196 scan blocks
#define NPACKB ((NNODES * 25 + 255) / 256) // 4883 pack blocks
#define NBN    (NNODES * DIM / 256)        // 25000 BN-apply blocks

using bf16x8 = __attribute__((ext_vector_type(8))) short;
using f32x4  = __attribute__((ext_vector_type(4))) float;

static constexpr size_t alignup(size_t x) { return (x + 255) & ~size_t(255); }
static constexpr size_t OFF_X    = 0;                                              // fp32 x (residual)
static constexpr size_t OFF_H    = alignup(OFF_X   + (size_t)NNODES * DIM * 4);    // bf16 H
static constexpr size_t OFF_O    = alignup(OFF_H   + (size_t)NNODES * DIM * 2);    // fp32 out
static constexpr size_t OFF_AB   = alignup(OFF_O   + (size_t)NNODES * DIM * 4);    // bf16 A=[x|PE|0]
static constexpr size_t OFF_HL   = alignup(OFF_AB  + (size_t)NNODES * KPAD * 2);
static constexpr size_t OFF_HR   = alignup(OFF_HL  + (size_t)NNODES * 4);
static constexpr size_t OFF_OFFS = alignup(OFF_HR  + (size_t)NNODES * 4);
static constexpr size_t OFF_CUR  = alignup(OFF_OFFS + (size_t)(NNODES + 1) * 4);
static constexpr size_t OFF_CSR  = alignup(OFF_CUR + (size_t)NNODES * 4);
static constexpr size_t OFF_BTG  = alignup(OFF_CSR + (size_t)NEDGES * 4);
static constexpr size_t OFF_B2   = alignup(OFF_BTG + (size_t)DIM * KPAD * 2);
static constexpr size_t OFF_ET   = alignup(OFF_B2  + (size_t)DIM * 4);
static constexpr size_t OFF_GS   = alignup(OFF_ET  + 16 * 4);                      // 4*128 floats: gs0,gsq0,gs1,gsq1
static constexpr size_t OFF_BS   = alignup(OFF_GS  + 512 * 4);
static constexpr size_t OFF_BP   = alignup(OFF_BS  + 256 * 4);
static constexpr size_t WS_NEED  = alignup(OFF_BP  + 256 * 4);

__device__ inline unsigned short f2b(float f) {
    union { float f; unsigned int u; } x; x.f = f;
    unsigned int r = x.u + 0x7FFFu + ((x.u >> 16) & 1u);
    return (unsigned short)(r >> 16);
}
__device__ inline unsigned int pack2(float a, float b) {
    return (unsigned int)f2b(a) | ((unsigned int)f2b(b) << 16);
}

__device__ inline void gload_lds16(const void* g, void* l) {
    __builtin_amdgcn_global_load_lds((const __attribute__((address_space(1))) void*)g,
                                     (__attribute__((address_space(3))) void*)l, 16, 0, 0);
}

// ---------------- CSR build ----------------

__global__ void k_zero_int(int* __restrict__ p, int n) {
    for (int i = blockIdx.x * blockDim.x + threadIdx.x; i < n; i += gridDim.x * blockDim.x)
        p[i] = 0;
}

__global__ void k_count(const int* __restrict__ dstv, int* __restrict__ cnt) {
    for (int e = blockIdx.x * blockDim.x + threadIdx.x; e < NEDGES; e += gridDim.x * blockDim.x)
        atomicAdd(&cnt[dstv[e]], 1);
}

__global__ __launch_bounds__(256) void k_scan1(const int* __restrict__ cnt, int* __restrict__ bsum) {
    __shared__ int ls[256];
    const int i = blockIdx.x * 256 + threadIdx.x;
    ls[threadIdx.x] = (i < NNODES) ? cnt[i] : 0;
    __syncthreads();
    for (int d = 128; d > 0; d >>= 1) {
        if (threadIdx.x < d) ls[threadIdx.x] += ls[threadIdx.x + d];
        __syncthreads();
    }
    if (threadIdx.x == 0) bsum[blockIdx.x] = ls[0];
}

__global__ __launch_bounds__(256) void k_scan2(const int* __restrict__ bsum,
                                               int* __restrict__ bpre, int* __restrict__ offs) {
    __shared__ int ls[256];
    const int t = threadIdx.x;
    ls[t] = (t < NSB) ? bsum[t] : 0;
    __syncthreads();
    for (int d = 1; d < 256; d <<= 1) {
        int v = (t >= d) ? ls[t - d] : 0;
        __syncthreads();
        ls[t] += v;
        __syncthreads();
    }
    bpre[t] = (t == 0) ? 0 : ls[t - 1];
    if (t == 255) offs[NNODES] = ls[255];
}

__global__ __launch_bounds__(256) void k_scan3(const int* __restrict__ cnt,
                                               const int* __restrict__ bpre,
                                               int* __restrict__ offs, int* __restrict__ cur) {
    __shared__ int ls[256];
    const int i = blockIdx.x * 256 + threadIdx.x;
    const int v = (i < NNODES) ? cnt[i] : 0;
    ls[threadIdx.x] = v;
    __syncthreads();
    for (int d = 1; d < 256; d <<= 1) {
        int x = (threadIdx.x >= d) ? ls[threadIdx.x - d] : 0;
        __syncthreads();
        ls[threadIdx.x] += x;
        __syncthreads();
    }
    if (i < NNODES) {
        const int excl = ls[threadIdx.x] - v + bpre[blockIdx.x];
        offs[i] = excl;
        cur[i] = excl;
    }
}

__global__ void k_fill(const int* __restrict__ srcv, const int* __restrict__ dstv,
                       const int* __restrict__ attr, int* __restrict__ cur,
                       int* __restrict__ csr) {
    for (int e = blockIdx.x * blockDim.x + threadIdx.x; e < NEDGES; e += gridDim.x * blockDim.x) {
        int d = dstv[e];
        int pos = atomicAdd(&cur[d], 1);
        csr[pos] = (srcv[e] & 0xFFFF) | (attr[e] << 16);
    }
}

// ---------------- shared params body ----------------
__device__ inline void params_body(int pb, int tid,
    const float* __restrict__ linW, const float* __restrict__ peW,
    const float* __restrict__ peb, const float* __restrict__ attn_e,
    const float* __restrict__ edge_emb,
    unsigned short* __restrict__ Btg, float* __restrict__ b2, float* __restrict__ et) {
    if (pb < 100) {
        const int idx = pb * 256 + tid;   // 0..25599
        const int j = idx & 127;
        const int k = idx >> 7;           // 0..199
        float v = 0.f;
        if (k < DIM) {
            v = linW[k * DIM + j];
        } else if (k < KTOT) {
            const int p = k - DIM;
            float s = 0.f;
            #pragma unroll 8
            for (int d = 0; d < DIM; ++d) s = fmaf(peW[p * DIM + d], linW[d * DIM + j], s);
            v = s;
        }
        Btg[(size_t)j * KPAD + k] = f2b(v);
    } else {
        if (tid < DIM) {
            float s = 0.f;
            #pragma unroll 8
            for (int d = 0; d < DIM; ++d) s = fmaf(peb[d], linW[d * DIM + tid], s);
            b2[tid] = s;
        } else if (tid < DIM + 9) {
            const int e = tid - DIM;
            float s = 0.f;
            #pragma unroll 8
            for (int d = 0; d < DIM; ++d) s = fmaf(edge_emb[e * DIM + d], attn_e[d], s);
            et[e] = s;
        }
    }
}

// ---------------- pack A + layer-0 params + zero BN accumulators ----------------
__global__ __launch_bounds__(256) void k_pack(
    const float* __restrict__ X, const float* __restrict__ PE,
    const float* __restrict__ linW, const float* __restrict__ peW,
    const float* __restrict__ peb, const float* __restrict__ attn_e,
    const float* __restrict__ edge_emb,
    unsigned short* __restrict__ Ab, unsigned short* __restrict__ Btg,
    float* __restrict__ b2, float* __restrict__ et, float* __restrict__ gs) {
    if ((int)blockIdx.x < NPACKB) {
        const int idx = blockIdx.x * 256 + threadIdx.x;
        if (idx >= NNODES * 25) return;
        const int r = idx / 25, kc = idx % 25;
        int4 pk;
        if (kc < 16) {
            const float4* xp = (const float4*)&X[(size_t)r * DIM + kc * 8];
            const float4 v0 = xp[0], v1 = xp[1];
            pk.x = pack2(v0.x, v0.y); pk.y = pack2(v0.z, v0.w);
            pk.z = pack2(v1.x, v1.y); pk.w = pack2(v1.z, v1.w);
        } else {
            float f[8];
            #pragma unroll
            for (int i = 0; i < 8; ++i) {
                const int k = kc * 8 + i;
                f[i] = (k < KTOT) ? PE[(size_t)r * PEDIM + (k - DIM)] : 0.f;
            }
            pk.x = pack2(f[0], f[1]); pk.y = pack2(f[2], f[3]);
            pk.z = pack2(f[4], f[5]); pk.w = pack2(f[6], f[7]);
        }
        ((int4*)(Ab + (size_t)r * KPAD))[kc] = pk;
    } else {
        const int pb = blockIdx.x - NPACKB;
        if (pb == 100) {
            gs[threadIdx.x] = 0.f;
            gs[threadIdx.x + 256] = 0.f;
        }
        params_body(pb, threadIdx.x, linW, peW, peb, attn_e, edge_emb, Btg, b2, et);
    }
}

// ---------------- MFMA GEMM: H(bf16) = A @ B + b2, plus hl/hr ----------------
// BM=64, N=128, K=192. Only B in LDS (51.2 KB -> 3 blocks/CU); A frags global->VGPR.
__global__ __launch_bounds__(256) void k_gemm(
    const unsigned short* __restrict__ Ab16, const unsigned short* __restrict__ Btg,
    const float* __restrict__ b2, const float* __restrict__ attn_l,
    const float* __restrict__ attn_r,
    unsigned short* __restrict__ H, float* __restrict__ HL, float* __restrict__ HR) {
    __shared__ unsigned short Bls[DIM * KPAD];   // 51.2 KB
    const int tid = threadIdx.x;
    const int row0 = blockIdx.x * 64;
    const int w = tid >> 6, l = tid & 63;
    const int c = l & 15;     // A-row-in-tile / B-col / D-col
    const int g = l >> 4;     // k-subgroup / D-row-group

    // issue A fragment loads first (overlap with B staging). OOB rows read
    // garbage inside ws (harmless; outputs guarded), last block only.
    const unsigned short* aBase = Ab16 + (size_t)(row0 + w * 16 + c) * KPAD + g * 8;
    bf16x8 a0 = *(const bf16x8*)(aBase + 0 * 32);
    bf16x8 a1 = *(const bf16x8*)(aBase + 1 * 32);
    bf16x8 a2 = *(const bf16x8*)(aBase + 2 * 32);
    bf16x8 a3 = *(const bf16x8*)(aBase + 3 * 32);
    bf16x8 a4 = *(const bf16x8*)(aBase + 4 * 32);
    bf16x8 a5 = *(const bf16x8*)(aBase + 5 * 32);

    {   // stage B: 3200 int4, linear
        const int4* gb = (const int4*)Btg;
        int4* lb = (int4*)Bls;
        for (int i = tid; i < 3200; i += 256) gload_lds16(gb + i, lb + i);
    }
    __syncthreads();

    f32x4 zero4 = {0.f, 0.f, 0.f, 0.f};
    f32x4 acc[8];
    #pragma unroll
    for (int t = 0; t < 8; ++t) acc[t] = zero4;

    #pragma unroll
    for (int t = 0; t < 8; ++t) {
        const unsigned short* bRow = Bls + (size_t)(t * 16 + c) * KPAD + g * 8;
        acc[t] = __builtin_amdgcn_mfma_f32_16x16x32_bf16(a0, *(const bf16x8*)(bRow + 0 * 32), acc[t], 0, 0, 0);
        acc[t] = __builtin_amdgcn_mfma_f32_16x16x32_bf16(a1, *(const bf16x8*)(bRow + 1 * 32), acc[t], 0, 0, 0);
        acc[t] = __builtin_amdgcn_mfma_f32_16x16x32_bf16(a2, *(const bf16x8*)(bRow + 2 * 32), acc[t], 0, 0, 0);
        acc[t] = __builtin_amdgcn_mfma_f32_16x16x32_bf16(a3, *(const bf16x8*)(bRow + 3 * 32), acc[t], 0, 0, 0);
        acc[t] = __builtin_amdgcn_mfma_f32_16x16x32_bf16(a4, *(const bf16x8*)(bRow + 4 * 32), acc[t], 0, 0, 0);
        acc[t] = __builtin_amdgcn_mfma_f32_16x16x32_bf16(a5, *(const bf16x8*)(bRow + 5 * 32), acc[t], 0, 0, 0);
    }

    float b2v[8], alv[8], arv[8];
    #pragma unroll
    for (int t = 0; t < 8; ++t) {
        b2v[t] = b2[t * 16 + c];
        alv[t] = attn_l[t * 16 + c];
        arv[t] = attn_r[t * 16 + c];
    }
    #pragma unroll
    for (int t = 0; t < 8; ++t)
        #pragma unroll
        for (int j = 0; j < 4; ++j) acc[t][j] += b2v[t];

    #pragma unroll
    for (int j = 0; j < 4; ++j) {
        float sl = 0.f, sr = 0.f;
        #pragma unroll
        for (int t = 0; t < 8; ++t) { sl = fmaf(acc[t][j], alv[t], sl); sr = fmaf(acc[t][j], arv[t], sr); }
        #pragma unroll
        for (int m = 1; m < 16; m <<= 1) {
            sl += __shfl_xor(sl, m, 64);
            sr += __shfl_xor(sr, m, 64);
        }
        const int grow = row0 + w * 16 + g * 4 + j;
        if (grow < NNODES && c == 0) { HL[grow] = sl; HR[grow] = sr; }
    }

    // repack D tile -> bf16 via LDS (reuse Bls), then coalesced store
    __syncthreads();
    unsigned short* Hls = Bls;
    #pragma unroll
    for (int t = 0; t < 8; ++t)
        #pragma unroll
        for (int j = 0; j < 4; ++j)
            Hls[(w * 16 + g * 4 + j) * HSTR + t * 16 + c] = f2b(acc[t][j]);
    __syncthreads();
    #pragma unroll
    for (int kb = 0; kb < 4; ++kb) {
        const int idx = tid + kb * 256;         // 0..1023
        const int r = idx >> 4, kc = idx & 15;
        const int grow = row0 + r;
        if (grow < NNODES) {
            const int4 v = *(const int4*)(Hls + r * HSTR + kc * 8);
            ((int4*)(H + ((size_t)grow << 7)))[kc] = v;
        }
    }
}

// ---------------- per-node softmax + aggregation (one wave per node) ----------------
// 8 edge-groups x 8 lanes, edge loop unrolled x2 -> 16 edge-gathers in flight/wave.
// FINAL=0: OUT = agg + bias. FINAL=1: OUT = agg + bias + xprev -> d_out.
template<int FINAL>
__global__ __launch_bounds__(256) void k_agg(
    const int* __restrict__ offs, const int* __restrict__ csr,
    const float* __restrict__ HL, const float* __restrict__ HR,
    const float* __restrict__ et, const unsigned short* __restrict__ H,
    const float* __restrict__ bias, const float* __restrict__ xprev,
    float* __restrict__ OUT) {
    const int lane = threadIdx.x & 63;
    const int node = blockIdx.x * 4 + (threadIdx.x >> 6);
    if (node >= NNODES) return;
    const int off0 = offs[node];
    const int deg = offs[node + 1] - off0;

    const float hri = HR[node];
    float myA = 0.f;
    int myE = 0;          // init 0 -> invalid slots broadcast a safe, valid row id
    float mx = -1e30f;
    for (int j = lane; j < deg; j += 64) {
        const int en = csr[off0 + j];
        float al = HL[en & 0xFFFF] + hri + et[en >> 16];
        al = al > 0.f ? al : 0.2f * al;
        if (j < 64) { myA = al; myE = en & 0xFFFF; }
        mx = fmaxf(mx, al);
    }
    #pragma unroll
    for (int m = 1; m < 64; m <<= 1) mx = fmaxf(mx, __shfl_xor(mx, m, 64));

    float s = 0.f, wv = 0.f;
    const bool small = deg <= 64;
    if (small) {
        wv = (lane < deg) ? __expf(myA - mx) : 0.f;
        s = wv;
    } else {
        for (int j = lane; j < deg; j += 64) {
            const int en = csr[off0 + j];
            float al = HL[en & 0xFFFF] + hri + et[en >> 16];
            al = al > 0.f ? al : 0.2f * al;
            s += __expf(al - mx);
        }
    }
    #pragma unroll
    for (int m = 1; m < 64; m <<= 1) s += __shfl_xor(s, m, 64);
    const float invd = (deg > 0) ? 1.f / s : 0.f;
    wv *= invd;

    const int eg = lane >> 3, c = lane & 7;
    float a[16];
    #pragma unroll
    for (int t = 0; t < 16; ++t) a[t] = 0.f;

    if (small) {
        // unrolled x2: slots j0 = jb+eg, j1 = jb+eg+8; loads unconditional
        for (int jb = 0; jb < deg; jb += 16) {
            const int j0 = (jb + eg) & 63;
            const int j1 = (jb + eg + 8) & 63;
            float w0 = __shfl(wv, j0, 64);
            int   s0 = __shfl(myE, j0, 64);
            float w1 = __shfl(wv, j1, 64);
            int   s1 = __shfl(myE, j1, 64);
            if (jb + eg >= deg) w0 = 0.f;
            if (jb + eg + 8 >= deg) w1 = 0.f;
            const unsigned short* hp0 = H + ((size_t)s0 << 7) + (c << 4);
            const unsigned short* hp1 = H + ((size_t)s1 << 7) + (c << 4);
            const int4 hA = *(const int4*)hp0;
            const int4 hB = *(const int4*)(hp0 + 8);
            const int4 hC = *(const int4*)hp1;
            const int4 hD = *(const int4*)(hp1 + 8);
            const unsigned int uA[4] = {(unsigned)hA.x, (unsigned)hA.y, (unsigned)hA.z, (unsigned)hA.w};
            const unsigned int uB[4] = {(unsigned)hB.x, (unsigned)hB.y, (unsigned)hB.z, (unsigned)hB.w};
            const unsigned int uC[4] = {(unsigned)hC.x, (unsigned)hC.y, (unsigned)hC.z, (unsigned)hC.w};
            const unsigned int uD[4] = {(unsigned)hD.x, (unsigned)hD.y, (unsigned)hD.z, (unsigned)hD.w};
            #pragma unroll
            for (int q = 0; q < 4; ++q) {
                a[2 * q]     = fmaf(w0, __uint_as_float(uA[q] << 16), a[2 * q]);
                a[2 * q + 1] = fmaf(w0, __uint_as_float(uA[q] & 0xFFFF0000u), a[2 * q + 1]);
                a[8 + 2 * q]     = fmaf(w0, __uint_as_float(uB[q] << 16), a[8 + 2 * q]);
                a[8 + 2 * q + 1] = fmaf(w0, __uint_as_float(uB[q] & 0xFFFF0000u), a[8 + 2 * q + 1]);
            }
            #pragma unroll
            for (int q = 0; q < 4; ++q) {
                a[2 * q]     = fmaf(w1, __uint_as_float(uC[q] << 16), a[2 * q]);
                a[2 * q + 1] = fmaf(w1, __uint_as_float(uC[q] & 0xFFFF0000u), a[2 * q + 1]);
                a[8 + 2 * q]     = fmaf(w1, __uint_as_float(uD[q] << 16), a[8 + 2 * q]);
                a[8 + 2 * q + 1] = fmaf(w1, __uint_as_float(uD[q] & 0xFFFF0000u), a[8 + 2 * q + 1]);
            }
        }
    } else {
        for (int jb = 0; jb < deg; jb += 8) {
            const int j = jb + eg;
            float wgt = 0.f;
            int src = 0;
            if (j < deg) {
                const int en = csr[off0 + j];
                src = en & 0xFFFF;
                float al = HL[src] + hri + et[en >> 16];
                al = al > 0.f ? al : 0.2f * al;
                wgt = __expf(al - mx) * invd;
            }
            const unsigned short* hp = H + ((size_t)src << 7) + (c << 4);
            const int4 h0 = *(const int4*)hp;
            const int4 h1 = *(const int4*)(hp + 8);
            const unsigned int u[8] = {(unsigned)h0.x, (unsigned)h0.y, (unsigned)h0.z, (unsigned)h0.w,
                                       (unsigned)h1.x, (unsigned)h1.y, (unsigned)h1.z, (unsigned)h1.w};
            #pragma unroll
            for (int q = 0; q < 8; ++q) {
                a[2 * q]     = fmaf(wgt, __uint_as_float(u[q] << 16), a[2 * q]);
                a[2 * q + 1] = fmaf(wgt, __uint_as_float(u[q] & 0xFFFF0000u), a[2 * q + 1]);
            }
        }
    }

    #pragma unroll
    for (int m = 8; m < 64; m <<= 1)
        #pragma unroll
        for (int t = 0; t < 16; ++t) a[t] += __shfl_xor(a[t], m, 64);

    if (eg == 0) {
        const float* bp = bias + (c << 4);
        float* op = OUT + ((size_t)node << 7) + (c << 4);
        #pragma unroll
        for (int q = 0; q < 4; ++q) {
            const float4 b = *(const float4*)(bp + q * 4);
            float4 o = make_float4(a[q * 4] + b.x, a[q * 4 + 1] + b.y,
                                   a[q * 4 + 2] + b.z, a[q * 4 + 3] + b.w);
            if (FINAL) {
                const float4 xp = *(const float4*)(xprev + ((size_t)node << 7) + (c << 4) + q * 4);
                o.x += xp.x; o.y += xp.y; o.z += xp.z; o.w += xp.w;
            }
            *(float4*)(op + q * 4) = o;
        }
    }
}

// ---------------- BN stats (into per-layer gs: [gsum(128) | gsumsq(128)]) ----------------
__global__ __launch_bounds__(256) void k_bnstats(
    const float* __restrict__ OUT, float* __restrict__ gs) {
    __shared__ float ls[256], ls2[256];
    const int c = threadIdx.x & 127;
    const int half = threadIdx.x >> 7;
    const int rend = min(NNODES, (int)(blockIdx.x * 256 + 256));
    float s = 0.f, s2 = 0.f;
    for (int r = blockIdx.x * 256 + half; r < rend; r += 2) {
        const float v = OUT[(size_t)r * DIM + c];
        s += v;
        s2 = fmaf(v, v, s2);
    }
    ls[threadIdx.x] = s;
    ls2[threadIdx.x] = s2;
    __syncthreads();
    if (half == 0) {
        atomicAdd(&gs[c], ls[c] + ls[c + 128]);
        atomicAdd(&gs[128 + c], ls2[c] + ls2[c + 128]);
    }
}

// ---------------- BN apply + residual + A-repack, fused with NEXT layer's params ----------------
__global__ __launch_bounds__(256) void k_apply_bn_params(
    const float* __restrict__ OUT, const float* __restrict__ XPREV,
    const float* __restrict__ gs, const float* __restrict__ gamma,
    const float* __restrict__ beta,
    float* __restrict__ XNEXT, unsigned short* __restrict__ Ab,
    const float* __restrict__ linW, const float* __restrict__ peW,
    const float* __restrict__ peb, const float* __restrict__ attn_e,
    const float* __restrict__ edge_emb,
    unsigned short* __restrict__ Btg, float* __restrict__ b2, float* __restrict__ et) {
    if ((int)blockIdx.x < NBN) {
        const int idx = blockIdx.x * 256 + threadIdx.x;
        const int r = idx >> 7, c = idx & 127;
        const float mu = gs[c] * (1.f / NNODES);
        const float var = gs[128 + c] * (1.f / NNODES) - mu * mu;
        const float sc = gamma[c] * rsqrtf(var + 1e-5f);
        const float xn = (OUT[idx] - mu) * sc + beta[c] + XPREV[idx];
        XNEXT[idx] = xn;
        Ab[(size_t)r * KPAD + c] = f2b(xn);
    } else {
        params_body(blockIdx.x - NBN, threadIdx.x, linW, peW, peb, attn_e, edge_emb, Btg, b2, et);
    }
}

// ---------------- host ----------------
extern "C" void kernel_launch(void* const* d_in, const int* in_sizes, int n_in,
                              void* d_out, int out_size, void* d_ws, size_t ws_size,
                              hipStream_t stream) {
    const float* X_n      = (const float*)d_in[0];
    const float* PE       = (const float*)d_in[1];
    const int*   eidx     = (const int*)d_in[2];
    const int*   eattr    = (const int*)d_in[3];
    const float* edge_emb = (const float*)d_in[4];
    const float* pe_W     = (const float*)d_in[5];
    const float* pe_b     = (const float*)d_in[6];
    const float* lin_W    = (const float*)d_in[7];
    const float* attn_l   = (const float*)d_in[8];
    const float* attn_r   = (const float*)d_in[9];
    const float* attn_e   = (const float*)d_in[10];
    const float* bias     = (const float*)d_in[11];
    const float* bng      = (const float*)d_in[12];
    const float* bnb      = (const float*)d_in[13];

    if (ws_size < WS_NEED) return;

    char* ws = (char*)d_ws;
    float* xbuf   = (float*)(ws + OFF_X);
    unsigned short* hbuf = (unsigned short*)(ws + OFF_H);
    float* obuf   = (float*)(ws + OFF_O);
    unsigned short* Ab16 = (unsigned short*)(ws + OFF_AB);
    float* hl     = (float*)(ws + OFF_HL);
    float* hr     = (float*)(ws + OFF_HR);
    int*   offs   = (int*)(ws + OFF_OFFS);
    int*   cur    = (int*)(ws + OFF_CUR);
    int*   csr    = (int*)(ws + OFF_CSR);
    unsigned short* Btg = (unsigned short*)(ws + OFF_BTG);
    float* b2     = (float*)(ws + OFF_B2);
    float* et     = (float*)(ws + OFF_ET);
    float* gs     = (float*)(ws + OFF_GS);   // gs + 256*l for layer l
    int*   bsum   = (int*)(ws + OFF_BS);
    int*   bpre   = (int*)(ws + OFF_BP);

    const int* srcv = eidx;
    const int* dstv = eidx + NEDGES;

    hipLaunchKernelGGL(k_zero_int, dim3(256), dim3(256), 0, stream, cur, NNODES);
    hipLaunchKernelGGL(k_count, dim3(1024), dim3(256), 0, stream, dstv, cur);
    hipLaunchKernelGGL(k_scan1, dim3(NSB), dim3(256), 0, stream, cur, bsum);
    hipLaunchKernelGGL(k_scan2, dim3(1), dim3(256), 0, stream, bsum, bpre, offs);
    hipLaunchKernelGGL(k_scan3, dim3(NSB), dim3(256), 0, stream, cur, bpre, offs, cur);
    hipLaunchKernelGGL(k_fill, dim3(1024), dim3(256), 0, stream, srcv, dstv, eattr, cur, csr);
    hipLaunchKernelGGL(k_pack, dim3(NPACKB + 101), dim3(256), 0, stream,
                       X_n, PE, lin_W, pe_W, pe_b, attn_e, edge_emb,
                       Ab16, Btg, b2, et, gs);

    const float* xin = X_n;
    for (int l = 0; l < NLAYERS; ++l) {
        hipLaunchKernelGGL(k_gemm, dim3((NNODES + 63) / 64), dim3(256), 0, stream,
                           Ab16, Btg, b2, attn_l + (size_t)l * DIM, attn_r + (size_t)l * DIM,
                           hbuf, hl, hr);
        if (l < NLAYERS - 1) {
            hipLaunchKernelGGL((k_agg<0>), dim3((NNODES + 3) / 4), dim3(256), 0, stream,
                               offs, csr, hl, hr, et, hbuf, bias + (size_t)l * DIM,
                               (const float*)nullptr, obuf);
            hipLaunchKernelGGL(k_bnstats, dim3(NSB), dim3(256), 0, stream,
                               obuf, gs + 256 * l);
            const int ln = l + 1;
            hipLaunchKernelGGL(k_apply_bn_params, dim3(NBN + 101), dim3(256), 0, stream,
                               obuf, xin, gs + 256 * l, bng + (size_t)l * DIM, bnb + (size_t)l * DIM,
                               xbuf, Ab16,
                               lin_W + (size_t)ln * DIM * DIM, pe_W + (size_t)ln * PEDIM * DIM,
                               pe_b + (size_t)ln * DIM, attn_e + (size_t)ln * DIM,
                               edge_emb + (size_t)ln * 9 * DIM,
                               Btg, b2, et);
            xin = xbuf;
        } else {
            hipLaunchKernelGGL((k_agg<1>), dim3((NNODES + 3) / 4), dim3(256), 0, stream,
                               offs, csr, hl, hr, et, hbuf, bias + (size_t)l * DIM,
                               xin, (float*)d_out);
        }
    }
}